// Round 5
// baseline (279.872 us; speedup 1.0000x reference)
//
#include <hip/hip_runtime.h>
#include <hip/hip_cooperative_groups.h>
#include <math.h>

namespace cg = cooperative_groups;

#define NQ   512
#define NKV  1280
#define CDIM 128

// workspace layout (float offsets)
#define OFF_WDSUM 0         // 3
#define OFF_KSAT  16        // 163840 [c=128][k=1280]
#define OFF_VSA   163856    // 163840 [k=1280][c=128]
#define OFF_KDAT  327696    // 163840
#define OFF_VDA   491536    // 163840
#define OFF_OUTSA 655376    // 65536  [n=512][c=128]
#define OFF_OUTDA 720912    // 65536
#define OFF_PSAT  786448    // 16384  proj_sa_w^T [j=128][c=128]
#define OFF_PDAT  802832    // 16384
#define OFF_GSAT  819216    // 32768  gate_sa_w^T [j=256][c=128]
#define OFF_GDAT  851984    // 32768  -> total 884752 floats = 3.5 MB

// block-local softmax over 1280 (2 rows) + AV + store. 640 threads, 10 waves.
// l{row}{slot}: slot a = k=t, slot b = k=t+640.
__device__ __forceinline__ void softmax_av(
    int t, float l00, float l01, float l10, float l11,
    float (&sc)[2][NKV], float (&part)[5][2][CDIM],
    float (&redm)[2][16], float (&reds)[2][16],
    const float* __restrict__ v, float* __restrict__ outp, int n0)
{
  int lane = t & 63, wv = t >> 6;
  float m0 = fmaxf(l00, l01), m1 = fmaxf(l10, l11);
  #pragma unroll
  for (int o = 32; o > 0; o >>= 1) {
    m0 = fmaxf(m0, __shfl_down(m0, o, 64));
    m1 = fmaxf(m1, __shfl_down(m1, o, 64));
  }
  if (lane == 0) { redm[0][wv] = m0; redm[1][wv] = m1; }
  __syncthreads();
  m0 = redm[0][0]; m1 = redm[1][0];
  #pragma unroll
  for (int w = 1; w < 10; ++w) {
    m0 = fmaxf(m0, redm[0][w]);
    m1 = fmaxf(m1, redm[1][w]);
  }
  float e00 = __expf(l00 - m0), e01 = __expf(l01 - m0);
  float e10 = __expf(l10 - m1), e11 = __expf(l11 - m1);
  sc[0][t] = e00; sc[0][t + 640] = e01;
  sc[1][t] = e10; sc[1][t + 640] = e11;
  float s0 = e00 + e01, s1 = e10 + e11;
  #pragma unroll
  for (int o = 32; o > 0; o >>= 1) {
    s0 += __shfl_down(s0, o, 64);
    s1 += __shfl_down(s1, o, 64);
  }
  if (lane == 0) { reds[0][wv] = s0; reds[1][wv] = s1; }
  __syncthreads();   // reds + sc visible
  // AV: c = t&127, k-split s = t>>7 in [0,5)
  int c = t & 127, sp = t >> 7;
  int kb = sp * 256;
  const float* vp = v + c;
  float a0 = 0.f, a1 = 0.f;
  #pragma unroll 2
  for (int ko = 0; ko < 256; ko += 4) {
    int k = kb + ko;
    float4 p0 = *(const float4*)&sc[0][k];
    float4 p1 = *(const float4*)&sc[1][k];
    float v0 = vp[(k + 0) * CDIM];
    float v1 = vp[(k + 1) * CDIM];
    float v2 = vp[(k + 2) * CDIM];
    float v3 = vp[(k + 3) * CDIM];
    a0 = fmaf(p0.x, v0, a0); a1 = fmaf(p1.x, v0, a1);
    a0 = fmaf(p0.y, v1, a0); a1 = fmaf(p1.y, v1, a1);
    a0 = fmaf(p0.z, v2, a0); a1 = fmaf(p1.z, v2, a1);
    a0 = fmaf(p0.w, v3, a0); a1 = fmaf(p1.w, v3, a1);
  }
  part[sp][0][c] = a0;
  part[sp][1][c] = a1;
  __syncthreads();
  if (t < 256) {
    int r = t >> 7, cc = t & 127;
    float ssum = reds[r][0];
    #pragma unroll
    for (int w = 1; w < 10; ++w) ssum += reds[r][w];
    float val = (part[0][r][cc] + part[1][r][cc] + part[2][r][cc]
               + part[3][r][cc] + part[4][r][cc]) / ssum;
    outp[(n0 + r) * CDIM + cc] = val;
  }
  __syncthreads();  // protect sc/part/red reuse by next branch
}

// grid 256 blocks x 640 threads (cooperative). Block b owns q-rows {2b,2b+1}
// (both branches), kv-rows [5b,5b+5), and a 384-elem slice of the transposes.
__global__ void __launch_bounds__(640) fused_kernel(
    const float* __restrict__ erp, const float* __restrict__ ico,
    const float* __restrict__ coord,
    const float* __restrict__ wq_sa, const float* __restrict__ wkv_sa,
    const float* __restrict__ psa, const float* __restrict__ bsa,
    const float* __restrict__ wq_da, const float* __restrict__ wkv_da,
    const float* __restrict__ wdelta,
    const float* __restrict__ pda, const float* __restrict__ bda,
    const float* __restrict__ gsa, const float* __restrict__ gda,
    float* __restrict__ out, float* __restrict__ ws)
{
  __shared__ float eq[2][CDIM];         // erp columns (q inputs)
  __shared__ float xrow[5][CDIM];       // ico rows
  __shared__ float qs[2][CDIM];         // q_sa
  __shared__ float qd[2][CDIM];         // q_da
  __shared__ float sc[2][NKV];          // probs (reused per branch)
  __shared__ float part[5][2][CDIM];
  __shared__ float redm[2][16];
  __shared__ float reds[2][16];
  __shared__ float qcr[2][3];
  __shared__ float wdl[3];
  __shared__ float sain[2][CDIM];
  __shared__ float dain[2][CDIM];
  __shared__ float cat2[2][2 * CDIM];
  __shared__ float gl[2][2][CDIM];

  cg::grid_group grid = cg::this_grid();
  int b = blockIdx.x, t = threadIdx.x;
  int n0 = b * 2;

  // ================= P1: staging + projections + transposes =================
  if (t < 256) { int r = t >> 7, j = t & 127; eq[r][j] = erp[j * NQ + n0 + r]; }
  { int ky = t >> 7, j = t & 127; xrow[ky][j] = ico[(b * 5 + ky) * CDIM + j]; }
  if (t < 2) {
    int n = n0 + t;
    float x = (float)(n & 31), y = (float)(n >> 5);
    float u  = (x - 16.5f) * 0.19634954084936207f;  // pi/16
    float vv = (y -  8.5f) * 0.19634954084936207f;
    float cv = cosf(vv);
    qcr[t][0] = cv * sinf(u);
    qcr[t][1] = sinf(vv);
    qcr[t][2] = cv * cosf(u);
  }
  __syncthreads();

  // kv projection: 5 keys x 256 outs = 1280 = 2 per thread
  #pragma unroll
  for (int it = 0; it < 2; ++it) {
    int idx = t + it * 640;
    int ky = idx >> 8, o = idx & 255;
    const float4* w1 = (const float4*)(wkv_sa + o * CDIM);
    const float4* w2 = (const float4*)(wkv_da + o * CDIM);
    const float4* xv4 = (const float4*)xrow[ky];
    float as0 = 0, as1 = 0, ad0 = 0, ad1 = 0;
    #pragma unroll 8
    for (int j4 = 0; j4 < 32; ++j4) {
      float4 wa = w1[j4];
      float4 wc = w2[j4];
      float4 xa = xv4[j4];
      as0 = fmaf(wa.x, xa.x, as0); as1 = fmaf(wa.y, xa.y, as1);
      as0 = fmaf(wa.z, xa.z, as0); as1 = fmaf(wa.w, xa.w, as1);
      ad0 = fmaf(wc.x, xa.x, ad0); ad1 = fmaf(wc.y, xa.y, ad1);
      ad0 = fmaf(wc.z, xa.z, ad0); ad1 = fmaf(wc.w, xa.w, ad1);
    }
    float as = as0 + as1, ad = ad0 + ad1;
    int kk = b * 5 + ky;
    if (o < 128) {
      ws[OFF_KSAT + o * NKV + kk] = as;
      ws[OFF_KDAT + o * NKV + kk] = ad;
    } else {
      int c = o - 128;
      ws[OFF_VSA + kk * CDIM + c] = as;
      ws[OFF_VDA + kk * CDIM + c] = ad;
    }
  }

  // q projection for this block's 2 rows, both branches (into LDS)
  if (t < 512) {
    int r = t >> 8, br = (t >> 7) & 1, c = t & 127;
    const float4* w4 = (const float4*)((br ? wq_da : wq_sa) + c * CDIM);
    const float4* e4 = (const float4*)eq[r];
    float a0 = 0, a1 = 0;
    #pragma unroll 8
    for (int j4 = 0; j4 < 32; ++j4) {
      float4 wv = w4[j4];
      float4 ev = e4[j4];
      a0 = fmaf(wv.x, ev.x, a0); a1 = fmaf(wv.y, ev.y, a1);
      a0 = fmaf(wv.z, ev.z, a0); a1 = fmaf(wv.w, ev.w, a1);
    }
    (br ? qd[r] : qs[r])[c] = a0 + a1;
  }

  // weight transposes for P3: 98304 elems / 256 blocks = 384 per block
  if (t < 384) {
    int e = b * 384 + t;
    float val; int dsto;
    if (e < 16384)      { int j = e >> 7, c = e & 127;
                          val = psa[c * CDIM + j]; dsto = OFF_PSAT + e; }
    else if (e < 32768) { int e2 = e - 16384; int j = e2 >> 7, c = e2 & 127;
                          val = pda[c * CDIM + j]; dsto = OFF_PDAT + e2; }
    else if (e < 65536) { int e2 = e - 32768; int j = e2 >> 7, c = e2 & 127;
                          val = gsa[c * 2 * CDIM + j]; dsto = OFF_GSAT + e2; }
    else                { int e2 = e - 65536; int j = e2 >> 7, c = e2 & 127;
                          val = gda[c * 2 * CDIM + j]; dsto = OFF_GDAT + e2; }
    ws[dsto] = val;
  }

  if (b == 0 && t < 3) {   // Wdelta.sum(0)
    float s = 0.f;
    for (int i = 0; i < 128; ++i) s += wdelta[i * 3 + t];
    ws[OFF_WDSUM + t] = s;
  }

  grid.sync();   // K/V/transposes/wdsum visible everywhere

  if (t < 3) wdl[t] = ws[OFF_WDSUM + t];   // visible after sa softmax syncs

  // ================= P2a: sa scores -> softmax -> AV =================
  {
    const float* kp = ws + OFF_KSAT + t;
    float a00 = 0, a01 = 0, a10 = 0, a11 = 0;
    #pragma unroll 4
    for (int j = 0; j < CDIM; ++j) {
      float ka = kp[j * NKV], kb2 = kp[j * NKV + 640];
      float q0 = qs[0][j], q1 = qs[1][j];
      a00 = fmaf(q0, ka, a00); a01 = fmaf(q0, kb2, a01);
      a10 = fmaf(q1, ka, a10); a11 = fmaf(q1, kb2, a11);
    }
    const float scl = 0.088388347648318447f;  // 128^-0.5
    softmax_av(t, a00 * scl, a01 * scl, a10 * scl, a11 * scl,
               sc, part, redm, reds, ws + OFF_VSA, ws + OFF_OUTSA, n0);
  }

  // ================= P2b: da scores -> softmax -> AV =================
  {
    const float* kdp = ws + OFF_KDAT + t;
    float d00 = 0, d01 = 0, d10 = 0, d11 = 0;
    #pragma unroll 2
    for (int j = 0; j < CDIM; ++j) {
      float ka = kdp[j * NKV], kb2 = kdp[j * NKV + 640];
      float q0 = qd[0][j], q1 = qd[1][j];
      d00 += __expf(-fabsf(q0 - ka)); d01 += __expf(-fabsf(q0 - kb2));
      d10 += __expf(-fabsf(q1 - ka)); d11 += __expf(-fabsf(q1 - kb2));
    }
    int k2 = t + 640;
    float c0a = coord[t * 3], c1a = coord[t * 3 + 1], c2a = coord[t * 3 + 2];
    float c0b = coord[k2 * 3], c1b = coord[k2 * 3 + 1], c2b = coord[k2 * 3 + 2];
    float w0 = wdl[0], w1 = wdl[1], w2 = wdl[2];
    float p0a = w0 * __expf(-fabsf(qcr[0][0] - c0a))
              + w1 * __expf(-fabsf(qcr[0][1] - c1a))
              + w2 * __expf(-fabsf(qcr[0][2] - c2a));
    float p0b = w0 * __expf(-fabsf(qcr[0][0] - c0b))
              + w1 * __expf(-fabsf(qcr[0][1] - c1b))
              + w2 * __expf(-fabsf(qcr[0][2] - c2b));
    float p1a = w0 * __expf(-fabsf(qcr[1][0] - c0a))
              + w1 * __expf(-fabsf(qcr[1][1] - c1a))
              + w2 * __expf(-fabsf(qcr[1][2] - c2a));
    float p1b = w0 * __expf(-fabsf(qcr[1][0] - c0b))
              + w1 * __expf(-fabsf(qcr[1][1] - c1b))
              + w2 * __expf(-fabsf(qcr[1][2] - c2b));
    const float i128 = 0.0078125f;
    softmax_av(t, (d00 + p0a) * i128, (d01 + p0b) * i128,
                  (d10 + p1a) * i128, (d11 + p1b) * i128,
               sc, part, redm, reds, ws + OFF_VDA, ws + OFF_OUTDA, n0);
  }

  grid.sync();   // OUTSA/OUTDA complete

  // ================= P3: finalize (2 rows per block) =================
  if (t < 512) {
    int rr = t >> 8, u = t & 255, h = u >> 7, c = u & 127;
    int i = n0 + rr;
    if (h == 0)
      sain[rr][c] = ws[OFF_OUTSA + ((i & 3) * 128 + c) * CDIM + (i >> 2)];
    else
      dain[rr][c] = ws[OFF_OUTDA + i * CDIM + c];
  }
  __syncthreads();
  if (t < 512) {
    int rr = t >> 8, u = t & 255, h = u >> 7, c = u & 127;
    const float* wT = ws + (h ? OFF_PDAT : OFF_PSAT);
    const float* in = h ? dain[rr] : sain[rr];
    float acc0 = 0, acc1 = 0;
    #pragma unroll 8
    for (int j = 0; j < CDIM; j += 2) {
      acc0 = fmaf(in[j],     wT[j * CDIM + c],       acc0);
      acc1 = fmaf(in[j + 1], wT[(j + 1) * CDIM + c], acc1);
    }
    cat2[rr][h * CDIM + c] = (h ? bda[c] : bsa[c]) + acc0 + acc1;
  }
  __syncthreads();
  if (t < 512) {
    int rr = t >> 8, u = t & 255, sel = u >> 7, c = u & 127;
    const float* gT = ws + (sel ? OFF_GDAT : OFF_GSAT);
    const float* cr = cat2[rr];
    float g0 = 0, g1 = 0;
    #pragma unroll 8
    for (int j = 0; j < 2 * CDIM; j += 2) {
      g0 = fmaf(cr[j],     gT[j * CDIM + c],       g0);
      g1 = fmaf(cr[j + 1], gT[(j + 1) * CDIM + c], g1);
    }
    gl[rr][sel][c] = 1.0f / (1.0f + __expf(-(g0 + g1)));
  }
  __syncthreads();
  if (t < 256) {
    int rr = t >> 7, c = t & 127;
    int i = n0 + rr;
    out[c * NQ + i] = gl[rr][0][c] * cat2[rr][c]
                    + gl[rr][1][c] * cat2[rr][CDIM + c];
  }
}

// ---------------------------------------------------------------- launch
extern "C" void kernel_launch(void* const* d_in, const int* in_sizes, int n_in,
                              void* d_out, int out_size, void* d_ws, size_t ws_size,
                              hipStream_t stream)
{
  (void)in_sizes; (void)n_in; (void)out_size; (void)ws_size;
  const float* erp       = (const float*)d_in[0];
  const float* ico       = (const float*)d_in[1];
  const float* coord     = (const float*)d_in[2];
  const float* wq_sa     = (const float*)d_in[3];
  const float* wkv_sa    = (const float*)d_in[4];
  const float* proj_sa_w = (const float*)d_in[5];
  const float* proj_sa_b = (const float*)d_in[6];
  const float* wq_da     = (const float*)d_in[7];
  const float* wkv_da    = (const float*)d_in[8];
  const float* wdelta    = (const float*)d_in[9];
  const float* proj_da_w = (const float*)d_in[10];
  const float* proj_da_b = (const float*)d_in[11];
  const float* gate_sa   = (const float*)d_in[12];
  const float* gate_da   = (const float*)d_in[13];
  float* out = (float*)d_out;
  float* ws  = (float*)d_ws;

  void* args[] = {
    (void*)&erp, (void*)&ico, (void*)&coord,
    (void*)&wq_sa, (void*)&wkv_sa, (void*)&proj_sa_w, (void*)&proj_sa_b,
    (void*)&wq_da, (void*)&wkv_da, (void*)&wdelta,
    (void*)&proj_da_w, (void*)&proj_da_b,
    (void*)&gate_sa, (void*)&gate_da,
    (void*)&out, (void*)&ws
  };
  hipLaunchCooperativeKernel((const void*)fused_kernel, dim3(256), dim3(640),
                             args, 0, stream);
}

// Round 6
// 179.360 us; speedup vs baseline: 1.5604x; 1.5604x over previous
//
#include <hip/hip_runtime.h>
#include <math.h>

#define NQ   512
#define NKV  1280
#define CDIM 128

// workspace layout (float offsets)
#define OFF_WDSUM 0        // 3
#define OFF_SUMS  16       // 1024: [br][512] row sums (zeroed by prep)
#define OFF_KSAT  1056     // 163840 [c=128][k=1280]
#define OFF_VSA   164896   // 163840 [k=1280][c=128]
#define OFF_KDAT  328736   // 163840
#define OFF_VDA   492576   // 163840
#define OFF_OUT   656416   // 131072: [br][512][128] unnormalized AV (zeroed)
// total 787488 floats = 3.15 MB

// ---------------------------------------------------------------- prep
// bx<320: kv projection (4 keys); bx==320: wdsum + zero sums;
// bx in [321,449): zero OUT.
__global__ __launch_bounds__(256) void prep_kernel(
    const float* __restrict__ ico,
    const float* __restrict__ wkv_sa, const float* __restrict__ wkv_da,
    const float* __restrict__ wdelta, float* __restrict__ ws)
{
  int bx = blockIdx.x, t = threadIdx.x;
  if (bx < 320) {
    __shared__ float x4[4 * CDIM];          // [j*4 + ky]
    int k0 = bx * 4;
    for (int i = t; i < 512; i += 256) {
      int ky = i >> 7, j = i & 127;
      x4[j * 4 + ky] = ico[(k0 + ky) * CDIM + j];
    }
    __syncthreads();
    const float4* wsa4 = (const float4*)(wkv_sa + t * CDIM);
    const float4* wda4 = (const float4*)(wkv_da + t * CDIM);
    float as0=0,as1=0,as2=0,as3=0, ad0=0,ad1=0,ad2=0,ad3=0;
    #pragma unroll 4
    for (int j4 = 0; j4 < 32; ++j4) {
      float4 wsv = wsa4[j4];
      float4 wdv = wda4[j4];
      float4 x0 = *(const float4*)&x4[(j4 * 4 + 0) * 4];
      float4 x1 = *(const float4*)&x4[(j4 * 4 + 1) * 4];
      float4 x2 = *(const float4*)&x4[(j4 * 4 + 2) * 4];
      float4 x3 = *(const float4*)&x4[(j4 * 4 + 3) * 4];
      as0 = fmaf(wsv.x, x0.x, as0); as1 = fmaf(wsv.x, x0.y, as1);
      as2 = fmaf(wsv.x, x0.z, as2); as3 = fmaf(wsv.x, x0.w, as3);
      ad0 = fmaf(wdv.x, x0.x, ad0); ad1 = fmaf(wdv.x, x0.y, ad1);
      ad2 = fmaf(wdv.x, x0.z, ad2); ad3 = fmaf(wdv.x, x0.w, ad3);
      as0 = fmaf(wsv.y, x1.x, as0); as1 = fmaf(wsv.y, x1.y, as1);
      as2 = fmaf(wsv.y, x1.z, as2); as3 = fmaf(wsv.y, x1.w, as3);
      ad0 = fmaf(wdv.y, x1.x, ad0); ad1 = fmaf(wdv.y, x1.y, ad1);
      ad2 = fmaf(wdv.y, x1.z, ad2); ad3 = fmaf(wdv.y, x1.w, ad3);
      as0 = fmaf(wsv.z, x2.x, as0); as1 = fmaf(wsv.z, x2.y, as1);
      as2 = fmaf(wsv.z, x2.z, as2); as3 = fmaf(wsv.z, x2.w, as3);
      ad0 = fmaf(wdv.z, x2.x, ad0); ad1 = fmaf(wdv.z, x2.y, ad1);
      ad2 = fmaf(wdv.z, x2.z, ad2); ad3 = fmaf(wdv.z, x2.w, ad3);
      as0 = fmaf(wsv.w, x3.x, as0); as1 = fmaf(wsv.w, x3.y, as1);
      as2 = fmaf(wsv.w, x3.z, as2); as3 = fmaf(wsv.w, x3.w, as3);
      ad0 = fmaf(wdv.w, x3.x, ad0); ad1 = fmaf(wdv.w, x3.y, ad1);
      ad2 = fmaf(wdv.w, x3.z, ad2); ad3 = fmaf(wdv.w, x3.w, ad3);
    }
    if (t < 128) {   // k features -> transposed [c][k]
      *(float4*)(ws + OFF_KSAT + t * NKV + k0) = make_float4(as0, as1, as2, as3);
      *(float4*)(ws + OFF_KDAT + t * NKV + k0) = make_float4(ad0, ad1, ad2, ad3);
    } else {         // v features -> [k][c]
      int c = t - 128;
      ws[OFF_VSA + (k0 + 0) * CDIM + c] = as0;
      ws[OFF_VSA + (k0 + 1) * CDIM + c] = as1;
      ws[OFF_VSA + (k0 + 2) * CDIM + c] = as2;
      ws[OFF_VSA + (k0 + 3) * CDIM + c] = as3;
      ws[OFF_VDA + (k0 + 0) * CDIM + c] = ad0;
      ws[OFF_VDA + (k0 + 1) * CDIM + c] = ad1;
      ws[OFF_VDA + (k0 + 2) * CDIM + c] = ad2;
      ws[OFF_VDA + (k0 + 3) * CDIM + c] = ad3;
    }
  } else if (bx == 320) {
    *(float4*)(ws + OFF_SUMS + t * 4) = make_float4(0.f, 0.f, 0.f, 0.f);
    if (t < 3) {   // Wdelta.sum(0)
      float s = 0.f;
      for (int i = 0; i < 128; ++i) s += wdelta[i * 3 + t];
      ws[OFF_WDSUM + t] = s;
    }
  } else {
    int base = OFF_OUT + (bx - 321) * 1024 + t * 4;
    *(float4*)(ws + base) = make_float4(0.f, 0.f, 0.f, 0.f);
  }
}

// ---------------------------------------------------------------- attn
// grid (128 q-groups, 2 branches, 5 k-splits), block 256.
// No-max softmax: e = exp(logit) directly (logits bounded ~[-0.5,1.3]).
// Each block: fused q-proj -> e for its 256-k slice -> atomicAdd row sums
// -> partial AV over slice -> atomicAdd into OUT.
__global__ __launch_bounds__(256) void attn_kernel(
    const float* __restrict__ erp, const float* __restrict__ coord,
    const float* __restrict__ wq_sa, const float* __restrict__ wq_da,
    float* __restrict__ ws)
{
  __shared__ float eq[4][CDIM];     // erp columns (4 q rows)
  __shared__ float qf[CDIM * 4];    // q as [j][r] float4
  __shared__ float se[4][256];      // exp values for this k-slice
  __shared__ float red[4][4];       // [wave][row]
  __shared__ float qcr[4][3];
  __shared__ float wdl[3];
  int t = threadIdx.x;
  int n0 = blockIdx.x * 4;
  int br = blockIdx.y;
  int z  = blockIdx.z;
  int k  = z * 256 + t;

  for (int i = t; i < 512; i += 256) {
    int r = i & 3, j = i >> 2;
    eq[r][j] = erp[j * NQ + n0 + r];
  }
  if (br) {
    if (t < 4) {
      int n = n0 + t;
      float x = (float)(n & 31), y = (float)(n >> 5);
      float u  = (x - 16.5f) * 0.19634954084936207f;  // pi/16
      float vv = (y -  8.5f) * 0.19634954084936207f;
      float cv = cosf(vv);
      qcr[t][0] = cv * sinf(u);
      qcr[t][1] = sinf(vv);
      qcr[t][2] = cv * cosf(u);
    }
    if (t >= 64 && t < 67) wdl[t - 64] = ws[OFF_WDSUM + t - 64];
  }
  __syncthreads();

  {  // fused q-proj: thread (c=t&127, rb=t>>7) -> rows rb, rb+2
    int c = t & 127, rb = t >> 7;
    const float4* w4 = (const float4*)((br ? wq_da : wq_sa) + c * CDIM);
    const float4* ea = (const float4*)eq[rb];
    const float4* eb = (const float4*)eq[rb + 2];
    float a0 = 0, a1 = 0, b0 = 0, b1 = 0;
    #pragma unroll 8
    for (int j4 = 0; j4 < 32; ++j4) {
      float4 wv = w4[j4];
      float4 xa = ea[j4];
      float4 xb = eb[j4];
      a0 = fmaf(wv.x, xa.x, a0); a1 = fmaf(wv.y, xa.y, a1);
      a0 = fmaf(wv.z, xa.z, a0); a1 = fmaf(wv.w, xa.w, a1);
      b0 = fmaf(wv.x, xb.x, b0); b1 = fmaf(wv.y, xb.y, b1);
      b0 = fmaf(wv.z, xb.z, b0); b1 = fmaf(wv.w, xb.w, b1);
    }
    qf[c * 4 + rb]     = a0 + a1;
    qf[c * 4 + rb + 2] = b0 + b1;
  }
  __syncthreads();

  float e0, e1, e2, e3;
  if (br == 0) {
    const float* kp = ws + OFF_KSAT + k;
    float a0 = 0, a1 = 0, a2 = 0, a3 = 0;
    #pragma unroll 8
    for (int j = 0; j < CDIM; ++j) {
      float kv = kp[j * NKV];
      float4 q = *(const float4*)&qf[j * 4];
      a0 = fmaf(q.x, kv, a0); a1 = fmaf(q.y, kv, a1);
      a2 = fmaf(q.z, kv, a2); a3 = fmaf(q.w, kv, a3);
    }
    const float scl = 0.088388347648318447f;  // 128^-0.5
    e0 = __expf(a0 * scl); e1 = __expf(a1 * scl);
    e2 = __expf(a2 * scl); e3 = __expf(a3 * scl);
  } else {
    const float* kp = ws + OFF_KDAT + k;
    float a0 = 0, a1 = 0, a2 = 0, a3 = 0;
    #pragma unroll 4
    for (int j = 0; j < CDIM; ++j) {
      float kv = kp[j * NKV];
      float4 q = *(const float4*)&qf[j * 4];
      a0 += __expf(-fabsf(q.x - kv)); a1 += __expf(-fabsf(q.y - kv));
      a2 += __expf(-fabsf(q.z - kv)); a3 += __expf(-fabsf(q.w - kv));
    }
    float c0 = coord[k * 3], c1 = coord[k * 3 + 1], c2 = coord[k * 3 + 2];
    float w0 = wdl[0], w1 = wdl[1], w2 = wdl[2];
    float p0 = w0 * __expf(-fabsf(qcr[0][0] - c0))
             + w1 * __expf(-fabsf(qcr[0][1] - c1))
             + w2 * __expf(-fabsf(qcr[0][2] - c2));
    float p1 = w0 * __expf(-fabsf(qcr[1][0] - c0))
             + w1 * __expf(-fabsf(qcr[1][1] - c1))
             + w2 * __expf(-fabsf(qcr[1][2] - c2));
    float p2 = w0 * __expf(-fabsf(qcr[2][0] - c0))
             + w1 * __expf(-fabsf(qcr[2][1] - c1))
             + w2 * __expf(-fabsf(qcr[2][2] - c2));
    float p3 = w0 * __expf(-fabsf(qcr[3][0] - c0))
             + w1 * __expf(-fabsf(qcr[3][1] - c1))
             + w2 * __expf(-fabsf(qcr[3][2] - c2));
    const float i128 = 0.0078125f;  // 1/C
    e0 = __expf((a0 + p0) * i128); e1 = __expf((a1 + p1) * i128);
    e2 = __expf((a2 + p2) * i128); e3 = __expf((a3 + p3) * i128);
  }

  se[0][t] = e0; se[1][t] = e1; se[2][t] = e2; se[3][t] = e3;
  float s0 = e0, s1 = e1, s2 = e2, s3 = e3;
  #pragma unroll
  for (int o = 32; o > 0; o >>= 1) {
    s0 += __shfl_down(s0, o, 64); s1 += __shfl_down(s1, o, 64);
    s2 += __shfl_down(s2, o, 64); s3 += __shfl_down(s3, o, 64);
  }
  int lane = t & 63, wv = t >> 6;
  if (lane == 0) {
    red[wv][0] = s0; red[wv][1] = s1; red[wv][2] = s2; red[wv][3] = s3;
  }
  __syncthreads();   // covers se[] and red[]
  if (t < 4)
    atomicAdd(ws + OFF_SUMS + br * 512 + n0 + t,
              red[0][t] + red[1][t] + red[2][t] + red[3][t]);

  // partial AV over this slice: thread (c=t&127, h=t>>7) -> rows h, h+2
  const float* v = ws + (br ? OFF_VDA : OFF_VSA) + z * 256 * CDIM;
  int c = t & 127, h = t >> 7;
  const float* vp = v + c;
  float acc0 = 0.f, acc1 = 0.f;
  #pragma unroll 2
  for (int ko = 0; ko < 256; ko += 4) {
    float4 pa = *(const float4*)&se[h][ko];
    float4 pb = *(const float4*)&se[h + 2][ko];
    float v0 = vp[(ko + 0) * CDIM];
    float v1 = vp[(ko + 1) * CDIM];
    float v2 = vp[(ko + 2) * CDIM];
    float v3 = vp[(ko + 3) * CDIM];
    acc0 = fmaf(pa.x, v0, acc0); acc1 = fmaf(pb.x, v0, acc1);
    acc0 = fmaf(pa.y, v1, acc0); acc1 = fmaf(pb.y, v1, acc1);
    acc0 = fmaf(pa.z, v2, acc0); acc1 = fmaf(pb.z, v2, acc1);
    acc0 = fmaf(pa.w, v3, acc0); acc1 = fmaf(pb.w, v3, acc1);
  }
  float* op = ws + OFF_OUT + br * (NQ * CDIM);
  atomicAdd(op + (n0 + h) * CDIM + c,     acc0);
  atomicAdd(op + (n0 + h + 2) * CDIM + c, acc1);
}

// ---------------------------------------------------------------- finalize
// one block (256 thr) per query row: normalize (divide by sums) with the
// reference's transpose-reshape on sa, project both (half-split), gate, fuse.
__global__ __launch_bounds__(256) void finalize_kernel(
    const float* __restrict__ psa, const float* __restrict__ bsa,
    const float* __restrict__ pda, const float* __restrict__ bda,
    const float* __restrict__ gsa, const float* __restrict__ gda,
    float* __restrict__ out, float* __restrict__ ws)
{
  __shared__ float sain[CDIM];
  __shared__ float dain[CDIM];
  __shared__ float cat[2 * CDIM];
  __shared__ float gl[2][CDIM];
  int i = blockIdx.x, t = threadIdx.x;
  int h = t >> 7, c = t & 127;
  if (h == 0) {
    // sa_in[i][c] = out_sa[(i%4)*128 + c][i/4] / sum_sa[(i%4)*128 + c]
    int row = (i & 3) * 128 + c;
    float s = ws[OFF_SUMS + row];
    sain[c] = ws[OFF_OUT + row * CDIM + (i >> 2)] / s;
  } else {
    float s = ws[OFF_SUMS + 512 + i];
    dain[c] = ws[OFF_OUT + NQ * CDIM + i * CDIM + c] / s;
  }
  __syncthreads();
  {
    const float4* w4 = (const float4*)((h ? pda : psa) + c * CDIM);
    const float* in = h ? dain : sain;
    float a0 = 0, a1 = 0, a2 = 0, a3 = 0;
    #pragma unroll 8
    for (int j4 = 0; j4 < 32; ++j4) {
      float4 wv = w4[j4];
      float4 xv = *(const float4*)&in[j4 * 4];
      a0 = fmaf(wv.x, xv.x, a0); a1 = fmaf(wv.y, xv.y, a1);
      a2 = fmaf(wv.z, xv.z, a2); a3 = fmaf(wv.w, xv.w, a3);
    }
    cat[h * CDIM + c] = (h ? bda[c] : bsa[c]) + (a0 + a1) + (a2 + a3);
  }
  __syncthreads();
  {
    const float4* g4 = (const float4*)((h ? gda : gsa) + c * 2 * CDIM);
    float a0 = 0, a1 = 0, a2 = 0, a3 = 0;
    #pragma unroll 8
    for (int j4 = 0; j4 < 64; ++j4) {
      float4 gv = g4[j4];
      float4 cv = *(const float4*)&cat[j4 * 4];
      a0 = fmaf(gv.x, cv.x, a0); a1 = fmaf(gv.y, cv.y, a1);
      a2 = fmaf(gv.z, cv.z, a2); a3 = fmaf(gv.w, cv.w, a3);
    }
    gl[h][c] = 1.0f / (1.0f + __expf(-((a0 + a1) + (a2 + a3))));
  }
  __syncthreads();
  if (t < 128)
    out[t * NQ + i] = gl[0][t] * cat[t] + gl[1][t] * cat[CDIM + t];
}

// ---------------------------------------------------------------- launch
extern "C" void kernel_launch(void* const* d_in, const int* in_sizes, int n_in,
                              void* d_out, int out_size, void* d_ws, size_t ws_size,
                              hipStream_t stream)
{
  (void)in_sizes; (void)n_in; (void)out_size; (void)ws_size;
  const float* erp       = (const float*)d_in[0];
  const float* ico       = (const float*)d_in[1];
  const float* coord     = (const float*)d_in[2];
  const float* wq_sa     = (const float*)d_in[3];
  const float* wkv_sa    = (const float*)d_in[4];
  const float* proj_sa_w = (const float*)d_in[5];
  const float* proj_sa_b = (const float*)d_in[6];
  const float* wq_da     = (const float*)d_in[7];
  const float* wkv_da    = (const float*)d_in[8];
  const float* wdelta    = (const float*)d_in[9];
  const float* proj_da_w = (const float*)d_in[10];
  const float* proj_da_b = (const float*)d_in[11];
  const float* gate_sa   = (const float*)d_in[12];
  const float* gate_da   = (const float*)d_in[13];
  float* out = (float*)d_out;
  float* ws  = (float*)d_ws;

  hipLaunchKernelGGL(prep_kernel, dim3(449), dim3(256), 0, stream,
                     ico, wkv_sa, wkv_da, wdelta, ws);
  hipLaunchKernelGGL(attn_kernel, dim3(128, 2, 5), dim3(256), 0, stream,
                     erp, coord, wq_sa, wq_da, ws);
  hipLaunchKernelGGL(finalize_kernel, dim3(512), dim3(256), 0, stream,
                     proj_sa_w, proj_sa_b, proj_da_w, proj_da_b,
                     gate_sa, gate_da, out, ws);
}

// Round 7
// 155.707 us; speedup vs baseline: 1.7974x; 1.1519x over previous
//
#include <hip/hip_runtime.h>
#include <math.h>

#define NQ   512
#define NKV  1280
#define CDIM 128

// workspace layout (float offsets)
#define OFF_WDSUM 0        // 3
#define OFF_SUMS  16       // 1024: [br][512] row sums (zeroed by prep)
#define OFF_QSA   1056     // 65536 [n=512][c=128]
#define OFF_QDA   66592    // 65536
#define OFF_KSAT  132128   // 163840 [c=128][k=1280]
#define OFF_VSA   295968   // 163840 [k=1280][c=128]
#define OFF_KDAT  459808   // 163840
#define OFF_VDA   623648   // 163840
#define OFF_OUT   787488   // 131072: [br][512][128] unnormalized AV (zeroed)
// total 918560 floats = 3.67 MB

// ---------------------------------------------------------------- prep
// bx<320: kv proj (4 keys); bx in [320,448): q proj (4 rows);
// bx==448: wdsum + zero sums; bx in [449,577): zero OUT.
__global__ __launch_bounds__(256) void prep_kernel(
    const float* __restrict__ erp, const float* __restrict__ ico,
    const float* __restrict__ wq_sa, const float* __restrict__ wq_da,
    const float* __restrict__ wkv_sa, const float* __restrict__ wkv_da,
    const float* __restrict__ wdelta, float* __restrict__ ws)
{
  int bx = blockIdx.x, t = threadIdx.x;
  if (bx < 320) {
    __shared__ float x4[4 * CDIM];          // [j*4 + ky]
    int k0 = bx * 4;
    for (int i = t; i < 512; i += 256) {
      int ky = i >> 7, j = i & 127;
      x4[j * 4 + ky] = ico[(k0 + ky) * CDIM + j];
    }
    __syncthreads();
    const float4* wsa4 = (const float4*)(wkv_sa + t * CDIM);
    const float4* wda4 = (const float4*)(wkv_da + t * CDIM);
    float as0=0,as1=0,as2=0,as3=0, ad0=0,ad1=0,ad2=0,ad3=0;
    #pragma unroll 4
    for (int j4 = 0; j4 < 32; ++j4) {
      float4 wsv = wsa4[j4];
      float4 wdv = wda4[j4];
      float4 x0 = *(const float4*)&x4[(j4 * 4 + 0) * 4];
      float4 x1 = *(const float4*)&x4[(j4 * 4 + 1) * 4];
      float4 x2 = *(const float4*)&x4[(j4 * 4 + 2) * 4];
      float4 x3 = *(const float4*)&x4[(j4 * 4 + 3) * 4];
      as0 = fmaf(wsv.x, x0.x, as0); as1 = fmaf(wsv.x, x0.y, as1);
      as2 = fmaf(wsv.x, x0.z, as2); as3 = fmaf(wsv.x, x0.w, as3);
      ad0 = fmaf(wdv.x, x0.x, ad0); ad1 = fmaf(wdv.x, x0.y, ad1);
      ad2 = fmaf(wdv.x, x0.z, ad2); ad3 = fmaf(wdv.x, x0.w, ad3);
      as0 = fmaf(wsv.y, x1.x, as0); as1 = fmaf(wsv.y, x1.y, as1);
      as2 = fmaf(wsv.y, x1.z, as2); as3 = fmaf(wsv.y, x1.w, as3);
      ad0 = fmaf(wdv.y, x1.x, ad0); ad1 = fmaf(wdv.y, x1.y, ad1);
      ad2 = fmaf(wdv.y, x1.z, ad2); ad3 = fmaf(wdv.y, x1.w, ad3);
      as0 = fmaf(wsv.z, x2.x, as0); as1 = fmaf(wsv.z, x2.y, as1);
      as2 = fmaf(wsv.z, x2.z, as2); as3 = fmaf(wsv.z, x2.w, as3);
      ad0 = fmaf(wdv.z, x2.x, ad0); ad1 = fmaf(wdv.z, x2.y, ad1);
      ad2 = fmaf(wdv.z, x2.z, ad2); ad3 = fmaf(wdv.z, x2.w, ad3);
      as0 = fmaf(wsv.w, x3.x, as0); as1 = fmaf(wsv.w, x3.y, as1);
      as2 = fmaf(wsv.w, x3.z, as2); as3 = fmaf(wsv.w, x3.w, as3);
      ad0 = fmaf(wdv.w, x3.x, ad0); ad1 = fmaf(wdv.w, x3.y, ad1);
      ad2 = fmaf(wdv.w, x3.z, ad2); ad3 = fmaf(wdv.w, x3.w, ad3);
    }
    if (t < 128) {   // k features -> transposed [c][k]
      *(float4*)(ws + OFF_KSAT + t * NKV + k0) = make_float4(as0, as1, as2, as3);
      *(float4*)(ws + OFF_KDAT + t * NKV + k0) = make_float4(ad0, ad1, ad2, ad3);
    } else {         // v features -> [k][c]
      int c = t - 128;
      ws[OFF_VSA + (k0 + 0) * CDIM + c] = as0;
      ws[OFF_VSA + (k0 + 1) * CDIM + c] = as1;
      ws[OFF_VSA + (k0 + 2) * CDIM + c] = as2;
      ws[OFF_VSA + (k0 + 3) * CDIM + c] = as3;
      ws[OFF_VDA + (k0 + 0) * CDIM + c] = ad0;
      ws[OFF_VDA + (k0 + 1) * CDIM + c] = ad1;
      ws[OFF_VDA + (k0 + 2) * CDIM + c] = ad2;
      ws[OFF_VDA + (k0 + 3) * CDIM + c] = ad3;
    }
  } else if (bx < 448) {
    // q projection, 4 rows; t<128 -> q_sa out c=t, t>=128 -> q_da out c=t-128
    __shared__ float q4[4 * CDIM];          // [j*4 + r]
    int n0 = (bx - 320) * 4;
    for (int i = t; i < 512; i += 256)
      q4[i] = erp[(i >> 2) * NQ + n0 + (i & 3)];
    __syncthreads();
    const float* w = (t < 128) ? wq_sa : wq_da;
    int c = t & 127;
    const float4* w4 = (const float4*)(w + c * CDIM);
    float a0 = 0.f, a1 = 0.f, a2 = 0.f, a3 = 0.f;
    #pragma unroll 8
    for (int j4 = 0; j4 < 32; ++j4) {
      float4 wv = w4[j4];
      float4 q0 = *(const float4*)&q4[(j4 * 4 + 0) * 4];
      float4 q1 = *(const float4*)&q4[(j4 * 4 + 1) * 4];
      float4 q2 = *(const float4*)&q4[(j4 * 4 + 2) * 4];
      float4 q3 = *(const float4*)&q4[(j4 * 4 + 3) * 4];
      a0 = fmaf(wv.x, q0.x, a0); a1 = fmaf(wv.x, q0.y, a1);
      a2 = fmaf(wv.x, q0.z, a2); a3 = fmaf(wv.x, q0.w, a3);
      a0 = fmaf(wv.y, q1.x, a0); a1 = fmaf(wv.y, q1.y, a1);
      a2 = fmaf(wv.y, q1.z, a2); a3 = fmaf(wv.y, q1.w, a3);
      a0 = fmaf(wv.z, q2.x, a0); a1 = fmaf(wv.z, q2.y, a1);
      a2 = fmaf(wv.z, q2.z, a2); a3 = fmaf(wv.z, q2.w, a3);
      a0 = fmaf(wv.w, q3.x, a0); a1 = fmaf(wv.w, q3.y, a1);
      a2 = fmaf(wv.w, q3.z, a2); a3 = fmaf(wv.w, q3.w, a3);
    }
    float* o = ws + ((t < 128) ? OFF_QSA : OFF_QDA);
    o[(n0 + 0) * CDIM + c] = a0;
    o[(n0 + 1) * CDIM + c] = a1;
    o[(n0 + 2) * CDIM + c] = a2;
    o[(n0 + 3) * CDIM + c] = a3;
  } else if (bx == 448) {
    *(float4*)(ws + OFF_SUMS + t * 4) = make_float4(0.f, 0.f, 0.f, 0.f);
    if (t < 3) {   // Wdelta.sum(0)
      float s = 0.f;
      for (int i = 0; i < 128; ++i) s += wdelta[i * 3 + t];
      ws[OFF_WDSUM + t] = s;
    }
  } else {
    int base = OFF_OUT + (bx - 449) * 1024 + t * 4;
    *(float4*)(ws + base) = make_float4(0.f, 0.f, 0.f, 0.f);
  }
}

// ---------------------------------------------------------------- attn
// grid (256 q-pairs, 2 branches, 5 k-splits), block 256, 2 q-rows.
// No-max softmax (logits bounded ~[-0.5,1.3], fp32-exact).
// e = exp(logit) -> atomicAdd row sums -> partial AV -> atomicAdd OUT.
__global__ __launch_bounds__(256) void attn_kernel(
    const float* __restrict__ coord, float* __restrict__ ws)
{
  __shared__ __align__(16) float q2[CDIM * 2];   // [j*2 + r]
  __shared__ __align__(16) float se[2][256];     // exp values, this k-slice
  __shared__ float red[4][2];                    // [wave][row]
  __shared__ float part[2][2][CDIM];             // [k-half][row][c]
  __shared__ float qcr[2][3];
  __shared__ float wdl[3];
  int t = threadIdx.x;
  int n0 = blockIdx.x * 2;
  int br = blockIdx.y;
  int z  = blockIdx.z;
  int k  = z * 256 + t;

  {  // stage q (2 rows) from ws
    int r = t >> 7, j = t & 127;
    const float* qsrc = ws + (br ? OFF_QDA : OFF_QSA);
    q2[j * 2 + r] = qsrc[(n0 + r) * CDIM + j];
  }
  if (br) {
    if (t < 2) {
      int n = n0 + t;
      float x = (float)(n & 31), y = (float)(n >> 5);
      float u  = (x - 16.5f) * 0.19634954084936207f;  // pi/16
      float vv = (y -  8.5f) * 0.19634954084936207f;
      float cv = cosf(vv);
      qcr[t][0] = cv * sinf(u);
      qcr[t][1] = sinf(vv);
      qcr[t][2] = cv * cosf(u);
    }
    if (t >= 64 && t < 67) wdl[t - 64] = ws[OFF_WDSUM + t - 64];
  }
  __syncthreads();

  float e0, e1;
  if (br == 0) {
    const float* kp = ws + OFF_KSAT + k;
    float a0 = 0.f, a1 = 0.f;
    #pragma unroll 8
    for (int j = 0; j < CDIM; ++j) {
      float kv = kp[j * NKV];
      float2 q = *(const float2*)&q2[j * 2];
      a0 = fmaf(q.x, kv, a0);
      a1 = fmaf(q.y, kv, a1);
    }
    const float scl = 0.088388347648318447f;  // 128^-0.5
    e0 = __expf(a0 * scl);
    e1 = __expf(a1 * scl);
  } else {
    const float* kp = ws + OFF_KDAT + k;
    float a0 = 0.f, a1 = 0.f;
    #pragma unroll 8
    for (int j = 0; j < CDIM; ++j) {
      float kv = kp[j * NKV];
      float2 q = *(const float2*)&q2[j * 2];
      a0 += __expf(-fabsf(q.x - kv));
      a1 += __expf(-fabsf(q.y - kv));
    }
    float c0 = coord[k * 3], c1 = coord[k * 3 + 1], c2 = coord[k * 3 + 2];
    float w0 = wdl[0], w1 = wdl[1], w2 = wdl[2];
    float p0 = w0 * __expf(-fabsf(qcr[0][0] - c0))
             + w1 * __expf(-fabsf(qcr[0][1] - c1))
             + w2 * __expf(-fabsf(qcr[0][2] - c2));
    float p1 = w0 * __expf(-fabsf(qcr[1][0] - c0))
             + w1 * __expf(-fabsf(qcr[1][1] - c1))
             + w2 * __expf(-fabsf(qcr[1][2] - c2));
    const float i128 = 0.0078125f;  // 1/C
    e0 = __expf((a0 + p0) * i128);
    e1 = __expf((a1 + p1) * i128);
  }

  se[0][t] = e0; se[1][t] = e1;
  float s0 = e0, s1 = e1;
  #pragma unroll
  for (int o = 32; o > 0; o >>= 1) {
    s0 += __shfl_down(s0, o, 64);
    s1 += __shfl_down(s1, o, 64);
  }
  int lane = t & 63, wv = t >> 6;
  if (lane == 0) { red[wv][0] = s0; red[wv][1] = s1; }
  __syncthreads();   // covers se[] and red[]
  if (t < 2)
    atomicAdd(ws + OFF_SUMS + br * 512 + n0 + t,
              red[0][t] + red[1][t] + red[2][t] + red[3][t]);

  // partial AV: thread (c=t&127, h=t>>7) -> both rows over k-half of 128
  const float* v = ws + (br ? OFF_VDA : OFF_VSA) + z * 256 * CDIM;
  int c = t & 127, h = t >> 7;
  const float* vp = v + h * 128 * CDIM + c;
  float acc0 = 0.f, acc1 = 0.f;
  #pragma unroll 2
  for (int ko = 0; ko < 128; ko += 4) {
    int kk = h * 128 + ko;
    float4 pa = *(const float4*)&se[0][kk];
    float4 pb = *(const float4*)&se[1][kk];
    float v0 = vp[(ko + 0) * CDIM];
    float v1 = vp[(ko + 1) * CDIM];
    float v2 = vp[(ko + 2) * CDIM];
    float v3 = vp[(ko + 3) * CDIM];
    acc0 = fmaf(pa.x, v0, acc0); acc1 = fmaf(pb.x, v0, acc1);
    acc0 = fmaf(pa.y, v1, acc0); acc1 = fmaf(pb.y, v1, acc1);
    acc0 = fmaf(pa.z, v2, acc0); acc1 = fmaf(pb.z, v2, acc1);
    acc0 = fmaf(pa.w, v3, acc0); acc1 = fmaf(pb.w, v3, acc1);
  }
  part[h][0][c] = acc0;
  part[h][1][c] = acc1;
  __syncthreads();
  {
    int r = t >> 7, cc = t & 127;
    float sum = part[0][r][cc] + part[1][r][cc];
    atomicAdd(ws + OFF_OUT + br * (NQ * CDIM) + (n0 + r) * CDIM + cc, sum);
  }
}

// ---------------------------------------------------------------- finalize
// one block (256 thr) per query row: normalize (divide by sums) with the
// reference's transpose-reshape on sa, project both (half-split), gate, fuse.
__global__ __launch_bounds__(256) void finalize_kernel(
    const float* __restrict__ psa, const float* __restrict__ bsa,
    const float* __restrict__ pda, const float* __restrict__ bda,
    const float* __restrict__ gsa, const float* __restrict__ gda,
    float* __restrict__ out, float* __restrict__ ws)
{
  __shared__ float sain[CDIM];
  __shared__ float dain[CDIM];
  __shared__ float cat[2 * CDIM];
  __shared__ float gl[2][CDIM];
  int i = blockIdx.x, t = threadIdx.x;
  int h = t >> 7, c = t & 127;
  if (h == 0) {
    // sa_in[i][c] = out_sa[(i%4)*128 + c][i/4] / sum_sa[(i%4)*128 + c]
    int row = (i & 3) * 128 + c;
    float s = ws[OFF_SUMS + row];
    sain[c] = ws[OFF_OUT + row * CDIM + (i >> 2)] / s;
  } else {
    float s = ws[OFF_SUMS + 512 + i];
    dain[c] = ws[OFF_OUT + NQ * CDIM + i * CDIM + c] / s;
  }
  __syncthreads();
  {
    const float4* w4 = (const float4*)((h ? pda : psa) + c * CDIM);
    const float* in = h ? dain : sain;
    float a0 = 0, a1 = 0, a2 = 0, a3 = 0;
    #pragma unroll 8
    for (int j4 = 0; j4 < 32; ++j4) {
      float4 wv = w4[j4];
      float4 xv = *(const float4*)&in[j4 * 4];
      a0 = fmaf(wv.x, xv.x, a0); a1 = fmaf(wv.y, xv.y, a1);
      a2 = fmaf(wv.z, xv.z, a2); a3 = fmaf(wv.w, xv.w, a3);
    }
    cat[h * CDIM + c] = (h ? bda[c] : bsa[c]) + (a0 + a1) + (a2 + a3);
  }
  __syncthreads();
  {
    const float4* g4 = (const float4*)((h ? gda : gsa) + c * 2 * CDIM);
    float a0 = 0, a1 = 0, a2 = 0, a3 = 0;
    #pragma unroll 8
    for (int j4 = 0; j4 < 64; ++j4) {
      float4 gv = g4[j4];
      float4 cv = *(const float4*)&cat[j4 * 4];
      a0 = fmaf(gv.x, cv.x, a0); a1 = fmaf(gv.y, cv.y, a1);
      a2 = fmaf(gv.z, cv.z, a2); a3 = fmaf(gv.w, cv.w, a3);
    }
    gl[h][c] = 1.0f / (1.0f + __expf(-((a0 + a1) + (a2 + a3))));
  }
  __syncthreads();
  if (t < 128)
    out[t * NQ + i] = gl[0][t] * cat[t] + gl[1][t] * cat[CDIM + t];
}

// ---------------------------------------------------------------- launch
extern "C" void kernel_launch(void* const* d_in, const int* in_sizes, int n_in,
                              void* d_out, int out_size, void* d_ws, size_t ws_size,
                              hipStream_t stream)
{
  (void)in_sizes; (void)n_in; (void)out_size; (void)ws_size;
  const float* erp       = (const float*)d_in[0];
  const float* ico       = (const float*)d_in[1];
  const float* coord     = (const float*)d_in[2];
  const float* wq_sa     = (const float*)d_in[3];
  const float* wkv_sa    = (const float*)d_in[4];
  const float* proj_sa_w = (const float*)d_in[5];
  const float* proj_sa_b = (const float*)d_in[6];
  const float* wq_da     = (const float*)d_in[7];
  const float* wkv_da    = (const float*)d_in[8];
  const float* wdelta    = (const float*)d_in[9];
  const float* proj_da_w = (const float*)d_in[10];
  const float* proj_da_b = (const float*)d_in[11];
  const float* gate_sa   = (const float*)d_in[12];
  const float* gate_da   = (const float*)d_in[13];
  float* out = (float*)d_out;
  float* ws  = (float*)d_ws;

  hipLaunchKernelGGL(prep_kernel, dim3(577), dim3(256), 0, stream,
                     erp, ico, wq_sa, wq_da, wkv_sa, wkv_da, wdelta, ws);
  hipLaunchKernelGGL(attn_kernel, dim3(256, 2, 5), dim3(256), 0, stream,
                     coord, ws);
  hipLaunchKernelGGL(finalize_kernel, dim3(512), dim3(256), 0, stream,
                     proj_sa_w, proj_sa_b, proj_da_w, proj_da_b,
                     gate_sa, gate_da, out, ws);
}

// Round 8
// 142.774 us; speedup vs baseline: 1.9602x; 1.0906x over previous
//
#include <hip/hip_runtime.h>
#include <math.h>

#define NQ   512
#define NKV  1280
#define CDIM 128

// workspace layout (float offsets)
#define OFF_WDSUM 0        // 3
#define OFF_SUMS  16       // 1024: [br][512] row sums (zeroed by prep)
#define OFF_QSA   1056     // 65536 [n=512][c=128]
#define OFF_QDA   66592    // 65536
#define OFF_KSAT  132128   // 163840 [c=128][k=1280]
#define OFF_VSA   295968   // 163840 [k=1280][c=128]
#define OFF_KDAT  459808   // 163840
#define OFF_VDA   623648   // 163840
#define OFF_OUT   787488   // 131072: [br][512][128] unnormalized AV (zeroed)
// total 918560 floats = 3.67 MB

// ---------------------------------------------------------------- prep
// bx<320: kv proj (4 keys); bx in [320,448): q proj (4 rows);
// bx==448: wdsum + zero sums; bx in [449,577): zero OUT.
__global__ __launch_bounds__(256) void prep_kernel(
    const float* __restrict__ erp, const float* __restrict__ ico,
    const float* __restrict__ wq_sa, const float* __restrict__ wq_da,
    const float* __restrict__ wkv_sa, const float* __restrict__ wkv_da,
    const float* __restrict__ wdelta, float* __restrict__ ws)
{
  int bx = blockIdx.x, t = threadIdx.x;
  if (bx < 320) {
    __shared__ float x4[4 * CDIM];          // [j*4 + ky]
    int k0 = bx * 4;
    for (int i = t; i < 512; i += 256) {
      int ky = i >> 7, j = i & 127;
      x4[j * 4 + ky] = ico[(k0 + ky) * CDIM + j];
    }
    __syncthreads();
    const float4* wsa4 = (const float4*)(wkv_sa + t * CDIM);
    const float4* wda4 = (const float4*)(wkv_da + t * CDIM);
    float as0=0,as1=0,as2=0,as3=0, ad0=0,ad1=0,ad2=0,ad3=0;
    #pragma unroll 4
    for (int j4 = 0; j4 < 32; ++j4) {
      float4 wsv = wsa4[j4];
      float4 wdv = wda4[j4];
      float4 x0 = *(const float4*)&x4[(j4 * 4 + 0) * 4];
      float4 x1 = *(const float4*)&x4[(j4 * 4 + 1) * 4];
      float4 x2 = *(const float4*)&x4[(j4 * 4 + 2) * 4];
      float4 x3 = *(const float4*)&x4[(j4 * 4 + 3) * 4];
      as0 = fmaf(wsv.x, x0.x, as0); as1 = fmaf(wsv.x, x0.y, as1);
      as2 = fmaf(wsv.x, x0.z, as2); as3 = fmaf(wsv.x, x0.w, as3);
      ad0 = fmaf(wdv.x, x0.x, ad0); ad1 = fmaf(wdv.x, x0.y, ad1);
      ad2 = fmaf(wdv.x, x0.z, ad2); ad3 = fmaf(wdv.x, x0.w, ad3);
      as0 = fmaf(wsv.y, x1.x, as0); as1 = fmaf(wsv.y, x1.y, as1);
      as2 = fmaf(wsv.y, x1.z, as2); as3 = fmaf(wsv.y, x1.w, as3);
      ad0 = fmaf(wdv.y, x1.x, ad0); ad1 = fmaf(wdv.y, x1.y, ad1);
      ad2 = fmaf(wdv.y, x1.z, ad2); ad3 = fmaf(wdv.y, x1.w, ad3);
      as0 = fmaf(wsv.z, x2.x, as0); as1 = fmaf(wsv.z, x2.y, as1);
      as2 = fmaf(wsv.z, x2.z, as2); as3 = fmaf(wsv.z, x2.w, as3);
      ad0 = fmaf(wdv.z, x2.x, ad0); ad1 = fmaf(wdv.z, x2.y, ad1);
      ad2 = fmaf(wdv.z, x2.z, ad2); ad3 = fmaf(wdv.z, x2.w, ad3);
      as0 = fmaf(wsv.w, x3.x, as0); as1 = fmaf(wsv.w, x3.y, as1);
      as2 = fmaf(wsv.w, x3.z, as2); as3 = fmaf(wsv.w, x3.w, as3);
      ad0 = fmaf(wdv.w, x3.x, ad0); ad1 = fmaf(wdv.w, x3.y, ad1);
      ad2 = fmaf(wdv.w, x3.z, ad2); ad3 = fmaf(wdv.w, x3.w, ad3);
    }
    if (t < 128) {   // k features -> transposed [c][k]
      *(float4*)(ws + OFF_KSAT + t * NKV + k0) = make_float4(as0, as1, as2, as3);
      *(float4*)(ws + OFF_KDAT + t * NKV + k0) = make_float4(ad0, ad1, ad2, ad3);
    } else {         // v features -> [k][c]
      int c = t - 128;
      ws[OFF_VSA + (k0 + 0) * CDIM + c] = as0;
      ws[OFF_VSA + (k0 + 1) * CDIM + c] = as1;
      ws[OFF_VSA + (k0 + 2) * CDIM + c] = as2;
      ws[OFF_VSA + (k0 + 3) * CDIM + c] = as3;
      ws[OFF_VDA + (k0 + 0) * CDIM + c] = ad0;
      ws[OFF_VDA + (k0 + 1) * CDIM + c] = ad1;
      ws[OFF_VDA + (k0 + 2) * CDIM + c] = ad2;
      ws[OFF_VDA + (k0 + 3) * CDIM + c] = ad3;
    }
  } else if (bx < 448) {
    // q projection, 4 rows; t<128 -> q_sa out c=t, t>=128 -> q_da out c=t-128
    __shared__ float q4[4 * CDIM];          // [j*4 + r]
    int n0 = (bx - 320) * 4;
    for (int i = t; i < 512; i += 256)
      q4[i] = erp[(i >> 2) * NQ + n0 + (i & 3)];
    __syncthreads();
    const float* w = (t < 128) ? wq_sa : wq_da;
    int c = t & 127;
    const float4* w4 = (const float4*)(w + c * CDIM);
    float a0 = 0.f, a1 = 0.f, a2 = 0.f, a3 = 0.f;
    #pragma unroll 8
    for (int j4 = 0; j4 < 32; ++j4) {
      float4 wv = w4[j4];
      float4 q0 = *(const float4*)&q4[(j4 * 4 + 0) * 4];
      float4 q1 = *(const float4*)&q4[(j4 * 4 + 1) * 4];
      float4 q2 = *(const float4*)&q4[(j4 * 4 + 2) * 4];
      float4 q3 = *(const float4*)&q4[(j4 * 4 + 3) * 4];
      a0 = fmaf(wv.x, q0.x, a0); a1 = fmaf(wv.x, q0.y, a1);
      a2 = fmaf(wv.x, q0.z, a2); a3 = fmaf(wv.x, q0.w, a3);
      a0 = fmaf(wv.y, q1.x, a0); a1 = fmaf(wv.y, q1.y, a1);
      a2 = fmaf(wv.y, q1.z, a2); a3 = fmaf(wv.y, q1.w, a3);
      a0 = fmaf(wv.z, q2.x, a0); a1 = fmaf(wv.z, q2.y, a1);
      a2 = fmaf(wv.z, q2.z, a2); a3 = fmaf(wv.z, q2.w, a3);
      a0 = fmaf(wv.w, q3.x, a0); a1 = fmaf(wv.w, q3.y, a1);
      a2 = fmaf(wv.w, q3.z, a2); a3 = fmaf(wv.w, q3.w, a3);
    }
    float* o = ws + ((t < 128) ? OFF_QSA : OFF_QDA);
    o[(n0 + 0) * CDIM + c] = a0;
    o[(n0 + 1) * CDIM + c] = a1;
    o[(n0 + 2) * CDIM + c] = a2;
    o[(n0 + 3) * CDIM + c] = a3;
  } else if (bx == 448) {
    *(float4*)(ws + OFF_SUMS + t * 4) = make_float4(0.f, 0.f, 0.f, 0.f);
    if (t < 3) {   // Wdelta.sum(0)
      float s = 0.f;
      for (int i = 0; i < 128; ++i) s += wdelta[i * 3 + t];
      ws[OFF_WDSUM + t] = s;
    }
  } else {
    int base = OFF_OUT + (bx - 449) * 1024 + t * 4;
    *(float4*)(ws + base) = make_float4(0.f, 0.f, 0.f, 0.f);
  }
}

// ---------------------------------------------------------------- attn
// 2560 blocks, 1D, da first (b<1280). Each block: 4 q-rows, 128-k slice.
// Score phase: each k handled by 2 threads (64 j's each), partials merged in
// LDS. No-max softmax (logits bounded ~[-0.5,1.3], fp32-exact):
// e = exp(logit) -> atomicAdd row sums -> AV over 128 ks -> atomicAdd OUT.
__global__ __launch_bounds__(256) void attn_kernel(
    const float* __restrict__ coord, float* __restrict__ ws)
{
  __shared__ __align__(16) float qjf[4 * CDIM];  // [j*4 + r]
  __shared__ __align__(16) float psc[2][4][128]; // [jh][r][k]
  __shared__ __align__(16) float posk[4][128];   // pos_aff (da only)
  __shared__ __align__(16) float se[4][128];     // exp(logit)
  __shared__ float red[2][4];
  __shared__ float qcr[4][3];
  __shared__ float wdl[3];
  int b = blockIdx.x, t = threadIdx.x;
  int br = (b < 1280) ? 1 : 0;        // da blocks dispatched first
  int bb = br ? b : b - 1280;
  int g = bb / 10, z = bb - g * 10;
  int n0 = g * 4, k0 = z * 128;

  const float* qsrc = ws + (br ? OFF_QDA : OFF_QSA);
  for (int i = t; i < 512; i += 256) {
    int r = i & 3, j = i >> 2;
    qjf[j * 4 + r] = qsrc[(n0 + r) * CDIM + j];
  }
  if (br) {
    if (t < 4) {
      int n = n0 + t;
      float x = (float)(n & 31), y = (float)(n >> 5);
      float u  = (x - 16.5f) * 0.19634954084936207f;  // pi/16
      float vv = (y -  8.5f) * 0.19634954084936207f;
      float cv = cosf(vv);
      qcr[t][0] = cv * sinf(u);
      qcr[t][1] = sinf(vv);
      qcr[t][2] = cv * cosf(u);
    }
    if (t >= 64 && t < 67) wdl[t - 64] = ws[OFF_WDSUM + t - 64];
  }
  __syncthreads();

  int kl = t & 127, jh = t >> 7;
  int k = k0 + kl;
  {  // partial scores over this thread's 64-j half
    const float* kp = ws + (br ? OFF_KDAT : OFF_KSAT) + k + jh * 64 * NKV;
    const float4* qj = (const float4*)&qjf[jh * 64 * 4];
    float a0 = 0.f, a1 = 0.f, a2 = 0.f, a3 = 0.f;
    if (br) {
      #pragma unroll 4
      for (int j = 0; j < 64; ++j) {
        float kv = kp[j * NKV];
        float4 q = qj[j];
        a0 += __expf(-fabsf(q.x - kv)); a1 += __expf(-fabsf(q.y - kv));
        a2 += __expf(-fabsf(q.z - kv)); a3 += __expf(-fabsf(q.w - kv));
      }
    } else {
      #pragma unroll 8
      for (int j = 0; j < 64; ++j) {
        float kv = kp[j * NKV];
        float4 q = qj[j];
        a0 = fmaf(q.x, kv, a0); a1 = fmaf(q.y, kv, a1);
        a2 = fmaf(q.z, kv, a2); a3 = fmaf(q.w, kv, a3);
      }
    }
    psc[jh][0][kl] = a0; psc[jh][1][kl] = a1;
    psc[jh][2][kl] = a2; psc[jh][3][kl] = a3;
    if (br && jh == 1) {   // pos_aff for k, all 4 rows
      float c0 = coord[k * 3], c1 = coord[k * 3 + 1], c2 = coord[k * 3 + 2];
      float w0 = wdl[0], w1 = wdl[1], w2 = wdl[2];
      #pragma unroll
      for (int r = 0; r < 4; ++r)
        posk[r][kl] = w0 * __expf(-fabsf(qcr[r][0] - c0))
                    + w1 * __expf(-fabsf(qcr[r][1] - c1))
                    + w2 * __expf(-fabsf(qcr[r][2] - c2));
    }
  }
  __syncthreads();

  if (t < 128) {  // merge partials, exp, reduce sums (waves 0-1)
    const float scl = 0.088388347648318447f;  // 128^-0.5
    const float i128 = 0.0078125f;            // 1/C
    float s[4];
    #pragma unroll
    for (int r = 0; r < 4; ++r) {
      float tot = psc[0][r][t] + psc[1][r][t];
      float l = br ? (tot + posk[r][t]) * i128 : tot * scl;
      float e = __expf(l);
      se[r][t] = e;
      s[r] = e;
    }
    #pragma unroll
    for (int o = 32; o > 0; o >>= 1) {
      s[0] += __shfl_down(s[0], o, 64); s[1] += __shfl_down(s[1], o, 64);
      s[2] += __shfl_down(s[2], o, 64); s[3] += __shfl_down(s[3], o, 64);
    }
    if ((t & 63) == 0) {
      int w = t >> 6;
      red[w][0] = s[0]; red[w][1] = s[1]; red[w][2] = s[2]; red[w][3] = s[3];
    }
  }
  __syncthreads();   // covers se[] and red[]
  if (t < 4)
    atomicAdd(ws + OFF_SUMS + br * 512 + n0 + t, red[0][t] + red[1][t]);

  // AV: thread (c=t&127, h=t>>7) -> rows h, h+2 over all 128 ks
  int c = t & 127, h = t >> 7;
  const float* vp = ws + (br ? OFF_VDA : OFF_VSA) + k0 * CDIM + c;
  float acc0 = 0.f, acc1 = 0.f;
  #pragma unroll 4
  for (int ko = 0; ko < 128; ko += 4) {
    float4 pa = *(const float4*)&se[h][ko];
    float4 pb = *(const float4*)&se[h + 2][ko];
    float v0 = vp[(ko + 0) * CDIM];
    float v1 = vp[(ko + 1) * CDIM];
    float v2 = vp[(ko + 2) * CDIM];
    float v3 = vp[(ko + 3) * CDIM];
    acc0 = fmaf(pa.x, v0, acc0); acc1 = fmaf(pb.x, v0, acc1);
    acc0 = fmaf(pa.y, v1, acc0); acc1 = fmaf(pb.y, v1, acc1);
    acc0 = fmaf(pa.z, v2, acc0); acc1 = fmaf(pb.z, v2, acc1);
    acc0 = fmaf(pa.w, v3, acc0); acc1 = fmaf(pb.w, v3, acc1);
  }
  float* op = ws + OFF_OUT + br * (NQ * CDIM);
  atomicAdd(op + (n0 + h) * CDIM + c,     acc0);
  atomicAdd(op + (n0 + h + 2) * CDIM + c, acc1);
}

// ---------------------------------------------------------------- finalize
// one block (256 thr) per 2 query rows: normalize (divide by sums) with the
// reference's transpose-reshape on sa, project both, gate, fuse, NCHW store.
__global__ __launch_bounds__(256) void finalize_kernel(
    const float* __restrict__ psa, const float* __restrict__ bsa,
    const float* __restrict__ pda, const float* __restrict__ bda,
    const float* __restrict__ gsa, const float* __restrict__ gda,
    float* __restrict__ out, float* __restrict__ ws)
{
  __shared__ float sain[2][CDIM];
  __shared__ float dain[2][CDIM];
  __shared__ float cat[2][2 * CDIM];
  __shared__ float gl[2][2][CDIM];
  int i0 = blockIdx.x * 2, t = threadIdx.x;
  int h = t >> 7, c = t & 127;
  #pragma unroll
  for (int rr = 0; rr < 2; ++rr) {
    int i = i0 + rr;
    if (h == 0) {
      // sa_in[i][c] = out_sa[(i%4)*128 + c][i/4] / sum_sa[(i%4)*128 + c]
      int row = (i & 3) * 128 + c;
      float s = ws[OFF_SUMS + row];
      sain[rr][c] = ws[OFF_OUT + row * CDIM + (i >> 2)] / s;
    } else {
      float s = ws[OFF_SUMS + 512 + i];
      dain[rr][c] = ws[OFF_OUT + NQ * CDIM + i * CDIM + c] / s;
    }
  }
  __syncthreads();
  {
    const float4* w4 = (const float4*)((h ? pda : psa) + c * CDIM);
    const float* in0 = h ? dain[0] : sain[0];
    const float* in1 = h ? dain[1] : sain[1];
    float a0 = 0, a1 = 0, b0 = 0, b1 = 0;
    #pragma unroll 8
    for (int j4 = 0; j4 < 32; ++j4) {
      float4 wv = w4[j4];
      float4 x0 = *(const float4*)&in0[j4 * 4];
      float4 x1 = *(const float4*)&in1[j4 * 4];
      a0 = fmaf(wv.x, x0.x, a0); a1 = fmaf(wv.y, x0.y, a1);
      a0 = fmaf(wv.z, x0.z, a0); a1 = fmaf(wv.w, x0.w, a1);
      b0 = fmaf(wv.x, x1.x, b0); b1 = fmaf(wv.y, x1.y, b1);
      b0 = fmaf(wv.z, x1.z, b0); b1 = fmaf(wv.w, x1.w, b1);
    }
    float bias = h ? bda[c] : bsa[c];
    cat[0][h * CDIM + c] = bias + a0 + a1;
    cat[1][h * CDIM + c] = bias + b0 + b1;
  }
  __syncthreads();
  {
    const float4* g4 = (const float4*)((h ? gda : gsa) + c * 2 * CDIM);
    float a0 = 0, a1 = 0, b0 = 0, b1 = 0;
    #pragma unroll 8
    for (int j4 = 0; j4 < 64; ++j4) {
      float4 gv = g4[j4];
      float4 c0 = *(const float4*)&cat[0][j4 * 4];
      float4 c1 = *(const float4*)&cat[1][j4 * 4];
      a0 = fmaf(gv.x, c0.x, a0); a1 = fmaf(gv.y, c0.y, a1);
      a0 = fmaf(gv.z, c0.z, a0); a1 = fmaf(gv.w, c0.w, a1);
      b0 = fmaf(gv.x, c1.x, b0); b1 = fmaf(gv.y, c1.y, b1);
      b0 = fmaf(gv.z, c1.z, b0); b1 = fmaf(gv.w, c1.w, b1);
    }
    gl[0][h][c] = 1.0f / (1.0f + __expf(-(a0 + a1)));
    gl[1][h][c] = 1.0f / (1.0f + __expf(-(b0 + b1)));
  }
  __syncthreads();
  {  // h selects row, c selects channel
    int i = i0 + h;
    out[c * NQ + i] = gl[h][0][c] * cat[h][c] + gl[h][1][c] * cat[h][CDIM + c];
  }
}

// ---------------------------------------------------------------- launch
extern "C" void kernel_launch(void* const* d_in, const int* in_sizes, int n_in,
                              void* d_out, int out_size, void* d_ws, size_t ws_size,
                              hipStream_t stream)
{
  (void)in_sizes; (void)n_in; (void)out_size; (void)ws_size;
  const float* erp       = (const float*)d_in[0];
  const float* ico       = (const float*)d_in[1];
  const float* coord     = (const float*)d_in[2];
  const float* wq_sa     = (const float*)d_in[3];
  const float* wkv_sa    = (const float*)d_in[4];
  const float* proj_sa_w = (const float*)d_in[5];
  const float* proj_sa_b = (const float*)d_in[6];
  const float* wq_da     = (const float*)d_in[7];
  const float* wkv_da    = (const float*)d_in[8];
  const float* wdelta    = (const float*)d_in[9];
  const float* proj_da_w = (const float*)d_in[10];
  const float* proj_da_b = (const float*)d_in[11];
  const float* gate_sa   = (const float*)d_in[12];
  const float* gate_da   = (const float*)d_in[13];
  float* out = (float*)d_out;
  float* ws  = (float*)d_ws;

  hipLaunchKernelGGL(prep_kernel, dim3(577), dim3(256), 0, stream,
                     erp, ico, wq_sa, wq_da, wkv_sa, wkv_da, wdelta, ws);
  hipLaunchKernelGGL(attn_kernel, dim3(2560), dim3(256), 0, stream,
                     coord, ws);
  hipLaunchKernelGGL(finalize_kernel, dim3(256), dim3(256), 0, stream,
                     proj_sa_w, proj_sa_b, proj_da_w, proj_da_b,
                     gate_sa, gate_da, out, ws);
}